// Round 15
// baseline (46.588 us; speedup 1.0000x reference)
//
#include <hip/hip_runtime.h>
#include <stdint.h>

// DGT forward = binary-tree descent on sign(pred_z[node]) + per-leaf lookup.
// R15: SPECULATIVE 2-LEVEL JUMP — the one lever untried: reduce the number
// of dependent hops. Per hop, load rows {n, 2n+1, 2n+2} concurrently,
// compute all 3 dots + 3 interleaved DPP reduces; sign(z_n) selects the
// child dot (no new load), sign(z_child) gives the grandchild. 10 serial
// hops -> 5. Extra FMA/bytes land on idle resources (VALU 27%, HBM 12%).
//
// W in bf16 (512KB ws copy, R13/R14-proven); x packed bf16 in 16 u32.
// Numerics (absmax=0.0 across R11-R14): EPS_TIE=0.02 (~12 sigma of bf16
// dot error); |z| < EPS -> exact f64 dot on ORIGINAL f32 x and W.
// Spill gate: WRITE_SIZE must stay ~8.2MB (output only).

#define BATCH   65536
#define IN_DIM  256
#define NLEAF   1024
#define OUT_DIM 16
#define EPS_TIE 0.02f
#define WB_U32  (1023 * 128)   // packed bf16 W: 128 u32 per row

#define DPP_QUAD_XOR1   0xB1
#define DPP_QUAD_XOR2   0x4E
#define DPP_HALF_MIRROR 0x141

template <int CTRL>
__device__ __forceinline__ float dpp_xfer(float v) {
    return __int_as_float(__builtin_amdgcn_update_dpp(
        0, __float_as_int(v), CTRL, 0xf, 0xf, true));
}
__device__ __forceinline__ float group8_sum(float v) {
    v += dpp_xfer<DPP_QUAD_XOR1>(v);
    v += dpp_xfer<DPP_QUAD_XOR2>(v);
    v += dpp_xfer<DPP_HALF_MIRROR>(v);
    return v;
}
__device__ __forceinline__ float group8_max(float v) {
    v = fmaxf(v, dpp_xfer<DPP_QUAD_XOR1>(v));
    v = fmaxf(v, dpp_xfer<DPP_QUAD_XOR2>(v));
    v = fmaxf(v, dpp_xfer<DPP_HALF_MIRROR>(v));
    return v;
}

__device__ __forceinline__ float blo(uint32_t u) { return __uint_as_float(u << 16); }
__device__ __forceinline__ float bhi(uint32_t u) { return __uint_as_float(u & 0xffff0000u); }

__device__ __forceinline__ uint32_t pkbf(float a, float b) {
    uint32_t ua = __float_as_uint(a), ub = __float_as_uint(b);
    uint32_t ra = (ua + 0x7fffu + ((ua >> 16) & 1u)) >> 16;
    uint32_t rb = (ub + 0x7fffu + ((ub >> 16) & 1u)) >> 16;
    return ra | (rb << 16);
}

// ---- prep: W_pred f32 -> packed bf16 (RNE) in d_ws ----
__global__ __launch_bounds__(256) void dgt_prep(
    const float* __restrict__ W, uint32_t* __restrict__ Wb)
{
    int i = blockIdx.x * 256 + threadIdx.x;
    if (i < WB_U32) Wb[i] = pkbf(W[2 * i], W[2 * i + 1]);
}

// Rare exact-sign fallback: f64 dot on ORIGINAL f32 x and W.
// Group-uniform entry (z bitwise-uniform across the 8-lane group).
__device__ __forceinline__ int tree_sign_f64(
    const float* __restrict__ xrow, const float* __restrict__ wrow,
    float bias, int l)
{
    double A0 = 0.0, A1 = 0.0, A2 = 0.0, A3 = 0.0;
    #pragma unroll
    for (int k = 0; k < 4; ++k) {
        float4 xa = *reinterpret_cast<const float4*>(xrow + k * 64 + l * 8);
        float4 xb = *reinterpret_cast<const float4*>(xrow + k * 64 + l * 8 + 4);
        float4 wa = *reinterpret_cast<const float4*>(wrow + k * 64 + l * 8);
        float4 wb = *reinterpret_cast<const float4*>(wrow + k * 64 + l * 8 + 4);
        A0 += (double)xa.x * (double)wa.x; A1 += (double)xa.y * (double)wa.y;
        A2 += (double)xa.z * (double)wa.z; A3 += (double)xa.w * (double)wa.w;
        A0 += (double)xb.x * (double)wb.x; A1 += (double)xb.y * (double)wb.y;
        A2 += (double)xb.z * (double)wb.z; A3 += (double)xb.w * (double)wb.w;
    }
    double Z = (A0 + A1) + (A2 + A3);
    #pragma unroll
    for (int off = 4; off > 0; off >>= 1)
        Z += __shfl_xor(Z, off, 64);
    Z += (double)bias;
    return (Z < 0.0) ? 1 : 0;
}

// Guarded sign: fast f32/bf16 path, exact-f64 fallback inside the band.
__device__ __forceinline__ int guarded_sign(
    float z, int nd, const float* __restrict__ xrow,
    const float* __restrict__ W_pred, const float* __restrict__ b_pred, int l)
{
    if (__builtin_expect(fabsf(z) >= EPS_TIE, 1)) return (z < 0.f) ? 1 : 0;
    return tree_sign_f64(xrow, W_pred + (size_t)nd * IN_DIM, b_pred[nd], l);
}

// ---- main: 256 threads = 4 waves; 8-lane groups -> 32 samples/block ----
__global__ __launch_bounds__(256, 2) void dgt_jump(
    const float* __restrict__ x,
    const uint32_t* __restrict__ Wb,
    const float* __restrict__ W_pred,
    const float* __restrict__ b_pred,
    const float* __restrict__ W_or,
    const float* __restrict__ a_std,
    float* __restrict__ out)
{
    const int lane = threadIdx.x & 63;
    const int wid  = threadIdx.x >> 6;
    const int l    = lane & 7;           // lane within 8-group
    const int g    = lane >> 3;          // group (sample) within wave
    const int sample = blockIdx.x * 32 + wid * 8 + g;

    // x: lane l owns elems c + 8l + {0..7}, c in {0,64,128,192};
    // loaded f32, packed to bf16 in 16 u32 registers (R13-proven).
    const float* xrow = x + (size_t)sample * IN_DIM;
    uint32_t p0, p1, p2, p3, p4, p5, p6, p7, p8, p9, p10, p11, p12, p13, p14, p15;
    {
        float4 a0 = *reinterpret_cast<const float4*>(xrow +   0 + l * 8);
        float4 b0 = *reinterpret_cast<const float4*>(xrow +   4 + l * 8);
        float4 a1 = *reinterpret_cast<const float4*>(xrow +  64 + l * 8);
        float4 b1 = *reinterpret_cast<const float4*>(xrow +  68 + l * 8);
        p0 = pkbf(a0.x, a0.y); p1 = pkbf(a0.z, a0.w);
        p2 = pkbf(b0.x, b0.y); p3 = pkbf(b0.z, b0.w);
        p4 = pkbf(a1.x, a1.y); p5 = pkbf(a1.z, a1.w);
        p6 = pkbf(b1.x, b1.y); p7 = pkbf(b1.z, b1.w);
        float4 a2 = *reinterpret_cast<const float4*>(xrow + 128 + l * 8);
        float4 b2 = *reinterpret_cast<const float4*>(xrow + 132 + l * 8);
        float4 a3 = *reinterpret_cast<const float4*>(xrow + 192 + l * 8);
        float4 b3 = *reinterpret_cast<const float4*>(xrow + 196 + l * 8);
        p8  = pkbf(a2.x, a2.y); p9  = pkbf(a2.z, a2.w);
        p10 = pkbf(b2.x, b2.y); p11 = pkbf(b2.z, b2.w);
        p12 = pkbf(a3.x, a3.y); p13 = pkbf(a3.z, a3.w);
        p14 = pkbf(b3.x, b3.y); p15 = pkbf(b3.z, b3.w);
    }

    int node = 0, pos = 0;

    // 5 hops x 2 levels. Per hop: 3 rows (parent + both children) loaded
    // together -> ONE load-wait resolves TWO levels.
    #pragma unroll
    for (int hop = 0; hop < 5; ++hop) {
        const int nL = 2 * node + 1, nR = 2 * node + 2;
        const uint32_t* wP = Wb + (size_t)node * 128;
        const uint32_t* wL = Wb + (size_t)nL   * 128;
        const uint32_t* wR = Wb + (size_t)nR   * 128;

        // 12 uint4 loads issued back-to-back (one vmcnt covers the hop).
        uint4 P0 = *reinterpret_cast<const uint4*>(wP +  0 + l * 4);
        uint4 P1 = *reinterpret_cast<const uint4*>(wP + 32 + l * 4);
        uint4 P2 = *reinterpret_cast<const uint4*>(wP + 64 + l * 4);
        uint4 P3 = *reinterpret_cast<const uint4*>(wP + 96 + l * 4);
        uint4 L0 = *reinterpret_cast<const uint4*>(wL +  0 + l * 4);
        uint4 L1 = *reinterpret_cast<const uint4*>(wL + 32 + l * 4);
        uint4 L2 = *reinterpret_cast<const uint4*>(wL + 64 + l * 4);
        uint4 L3 = *reinterpret_cast<const uint4*>(wL + 96 + l * 4);
        uint4 R0 = *reinterpret_cast<const uint4*>(wR +  0 + l * 4);
        uint4 R1 = *reinterpret_cast<const uint4*>(wR + 32 + l * 4);
        uint4 R2 = *reinterpret_cast<const uint4*>(wR + 64 + l * 4);
        uint4 R3 = *reinterpret_cast<const uint4*>(wR + 96 + l * 4);

        float bP = b_pred[node], bL = b_pred[nL], bR = b_pred[nR];

#define FMAU(ACC0, ACC1, U, P)                                   \
        ACC0 += blo(U) * blo(P); ACC1 += bhi(U) * bhi(P);
#define FMA4(ACC0, ACC1, ACC2, ACC3, UQ, Pa, Pb, Pc, Pd)         \
        FMAU(ACC0, ACC1, UQ.x, Pa) FMAU(ACC2, ACC3, UQ.y, Pb)    \
        FMAU(ACC0, ACC1, UQ.z, Pc) FMAU(ACC2, ACC3, UQ.w, Pd)

        float pa0 = 0.f, pa1 = 0.f, pa2 = 0.f, pa3 = 0.f;
        FMA4(pa0, pa1, pa2, pa3, P0, p0,  p1,  p2,  p3)
        FMA4(pa0, pa1, pa2, pa3, P1, p4,  p5,  p6,  p7)
        FMA4(pa0, pa1, pa2, pa3, P2, p8,  p9,  p10, p11)
        FMA4(pa0, pa1, pa2, pa3, P3, p12, p13, p14, p15)

        float la0 = 0.f, la1 = 0.f, la2 = 0.f, la3 = 0.f;
        FMA4(la0, la1, la2, la3, L0, p0,  p1,  p2,  p3)
        FMA4(la0, la1, la2, la3, L1, p4,  p5,  p6,  p7)
        FMA4(la0, la1, la2, la3, L2, p8,  p9,  p10, p11)
        FMA4(la0, la1, la2, la3, L3, p12, p13, p14, p15)

        float ra0 = 0.f, ra1 = 0.f, ra2 = 0.f, ra3 = 0.f;
        FMA4(ra0, ra1, ra2, ra3, R0, p0,  p1,  p2,  p3)
        FMA4(ra0, ra1, ra2, ra3, R1, p4,  p5,  p6,  p7)
        FMA4(ra0, ra1, ra2, ra3, R2, p8,  p9,  p10, p11)
        FMA4(ra0, ra1, ra2, ra3, R3, p12, p13, p14, p15)
#undef FMA4
#undef FMAU

        // Three interleaved DPP reduces (independent -> latency overlaps).
        float zP = group8_sum((pa0 + pa1) + (pa2 + pa3)) + bP;
        float zL = group8_sum((la0 + la1) + (la2 + la3)) + bL;
        float zR = group8_sum((ra0 + ra1) + (ra2 + ra3)) + bR;

        const int rP = guarded_sign(zP, node, xrow, W_pred, b_pred, l);
        const float zC  = rP ? zR : zL;
        const int nodeC = 2 * node + 1 + rP;
        const int rC = guarded_sign(zC, nodeC, xrow, W_pred, b_pred, l);

        pos  = 4 * pos + 2 * rP + rC;
        node = 2 * nodeC + 1 + rC;
    }
    const int leaf = pos;  // in [0, 1024)

    // Epilogue: lane l covers classes {2l, 2l+1}; tables are cache-resident.
    float zx = W_or[(size_t)(2 * l)     * NLEAF + leaf];
    float zy = W_or[(size_t)(2 * l + 1) * NLEAF + leaf];
    float m  = group8_max(fmaxf(zx, zy));
    float ex = __expf(zx - m), ey = __expf(zy - m);
    float s  = group8_sum(ex + ey);
    *reinterpret_cast<float2*>(out + (size_t)sample * OUT_DIM + 2 * l) =
        make_float2(ex / s, ey / s);

    float dx = a_std[(size_t)(2 * l)     * NLEAF + leaf];
    float dy = a_std[(size_t)(2 * l + 1) * NLEAF + leaf];
    *reinterpret_cast<float2*>(out + (size_t)BATCH * OUT_DIM
                               + (size_t)sample * OUT_DIM + 2 * l) =
        make_float2(fminf(fmaxf(dx, -20.f), 2.f),
                    fminf(fmaxf(dy, -20.f), 2.f));
}

// ---- fallback kernel (ws too small): R8 structure, f32 W direct ----
__device__ __forceinline__ int tree_sign_f64_r8(
    float4 x0, float4 x1, float4 x2, float4 x3,
    float4 x4, float4 x5, float4 x6, float4 x7,
    const float* wrow, float bias, int l)
{
    double A0 = 0.0, A1 = 0.0, A2 = 0.0, A3 = 0.0;
#define ACC64(K, XV)                                                        \
    {                                                                       \
        float4 w = *reinterpret_cast<const float4*>(wrow + (K)*32 + l * 4); \
        A0 += (double)XV.x * (double)w.x; A1 += (double)XV.y * (double)w.y; \
        A2 += (double)XV.z * (double)w.z; A3 += (double)XV.w * (double)w.w; \
    }
    ACC64(0, x0) ACC64(1, x1) ACC64(2, x2) ACC64(3, x3)
    ACC64(4, x4) ACC64(5, x5) ACC64(6, x6) ACC64(7, x7)
#undef ACC64
    double Z = (A0 + A1) + (A2 + A3);
    #pragma unroll
    for (int off = 4; off > 0; off >>= 1)
        Z += __shfl_xor(Z, off, 64);
    Z += (double)bias;
    return (Z < 0.0) ? 1 : 0;
}

__global__ __launch_bounds__(256, 2) void dgt_f32(
    const float* __restrict__ x,
    const float* __restrict__ W_pred,
    const float* __restrict__ b_pred,
    const float* __restrict__ W_or,
    const float* __restrict__ a_std,
    float* __restrict__ out)
{
    const int lane = threadIdx.x & 63;
    const int wid  = threadIdx.x >> 6;
    const int l    = lane & 7;
    const int g    = lane >> 3;
    const int sample = blockIdx.x * 32 + wid * 8 + g;

    const float* xrow = x + (size_t)sample * IN_DIM;
    float4 x0 = *reinterpret_cast<const float4*>(xrow +   0 + l * 4);
    float4 x1 = *reinterpret_cast<const float4*>(xrow +  32 + l * 4);
    float4 x2 = *reinterpret_cast<const float4*>(xrow +  64 + l * 4);
    float4 x3 = *reinterpret_cast<const float4*>(xrow +  96 + l * 4);
    float4 x4 = *reinterpret_cast<const float4*>(xrow + 128 + l * 4);
    float4 x5 = *reinterpret_cast<const float4*>(xrow + 160 + l * 4);
    float4 x6 = *reinterpret_cast<const float4*>(xrow + 192 + l * 4);
    float4 x7 = *reinterpret_cast<const float4*>(xrow + 224 + l * 4);

    int node = 0, pos = 0;
    float bcur = b_pred[0];
    const float* wrow = W_pred;

    #pragma unroll
    for (int lvl = 0; lvl < 10; ++lvl) {
        float4 w0 = *reinterpret_cast<const float4*>(wrow +   0 + l * 4);
        float4 w1 = *reinterpret_cast<const float4*>(wrow +  32 + l * 4);
        float4 w2 = *reinterpret_cast<const float4*>(wrow +  64 + l * 4);
        float4 w3 = *reinterpret_cast<const float4*>(wrow +  96 + l * 4);
        float4 w4 = *reinterpret_cast<const float4*>(wrow + 128 + l * 4);
        float4 w5 = *reinterpret_cast<const float4*>(wrow + 160 + l * 4);
        float4 w6 = *reinterpret_cast<const float4*>(wrow + 192 + l * 4);
        float4 w7 = *reinterpret_cast<const float4*>(wrow + 224 + l * 4);

        float bL = 0.f, bR = 0.f;
        if (lvl < 9) {
            bL = b_pred[2 * node + 1];
            bR = b_pred[2 * node + 2];
        }

        float a0, a1, a2, a3;
        a0  = x0.x * w0.x; a1  = x0.y * w0.y; a2  = x0.z * w0.z; a3  = x0.w * w0.w;
        a0 += x1.x * w1.x; a1 += x1.y * w1.y; a2 += x1.z * w1.z; a3 += x1.w * w1.w;
        a0 += x2.x * w2.x; a1 += x2.y * w2.y; a2 += x2.z * w2.z; a3 += x2.w * w2.w;
        a0 += x3.x * w3.x; a1 += x3.y * w3.y; a2 += x3.z * w3.z; a3 += x3.w * w3.w;
        a0 += x4.x * w4.x; a1 += x4.y * w4.y; a2 += x4.z * w4.z; a3 += x4.w * w4.w;
        a0 += x5.x * w5.x; a1 += x5.y * w5.y; a2 += x5.z * w5.z; a3 += x5.w * w5.w;
        a0 += x6.x * w6.x; a1 += x6.y * w6.y; a2 += x6.z * w6.z; a3 += x6.w * w6.w;
        a0 += x7.x * w7.x; a1 += x7.y * w7.y; a2 += x7.z * w7.z; a3 += x7.w * w7.w;
        float z = group8_sum((a0 + a1) + (a2 + a3)) + bcur;

        int right;
        if (__builtin_expect(fabsf(z) >= 1e-3f, 1))
            right = (z < 0.f) ? 1 : 0;
        else
            right = tree_sign_f64_r8(x0, x1, x2, x3, x4, x5, x6, x7,
                                     wrow, bcur, l);

        pos  = 2 * pos + right;
        node = 2 * node + 1 + right;
        if (lvl < 9) {
            bcur = right ? bR : bL;
            wrow = W_pred + (size_t)node * IN_DIM;
        }
    }
    const int leaf = pos;

    float zx = W_or[(size_t)(2 * l)     * NLEAF + leaf];
    float zy = W_or[(size_t)(2 * l + 1) * NLEAF + leaf];
    float m  = group8_max(fmaxf(zx, zy));
    float ex = __expf(zx - m), ey = __expf(zy - m);
    float s  = group8_sum(ex + ey);
    *reinterpret_cast<float2*>(out + (size_t)sample * OUT_DIM + 2 * l) =
        make_float2(ex / s, ey / s);

    float dx = a_std[(size_t)(2 * l)     * NLEAF + leaf];
    float dy = a_std[(size_t)(2 * l + 1) * NLEAF + leaf];
    *reinterpret_cast<float2*>(out + (size_t)BATCH * OUT_DIM
                               + (size_t)sample * OUT_DIM + 2 * l) =
        make_float2(fminf(fmaxf(dx, -20.f), 2.f),
                    fminf(fmaxf(dy, -20.f), 2.f));
}

extern "C" void kernel_launch(void* const* d_in, const int* in_sizes, int n_in,
                              void* d_out, int out_size, void* d_ws, size_t ws_size,
                              hipStream_t stream) {
    const float* x      = (const float*)d_in[0];
    const float* W_pred = (const float*)d_in[1];
    const float* b_pred = (const float*)d_in[2];
    const float* W_or   = (const float*)d_in[3];
    const float* a_std  = (const float*)d_in[4];
    float* out = (float*)d_out;

    if (ws_size >= (size_t)WB_U32 * 4) {
        uint32_t* Wb = (uint32_t*)d_ws;
        hipLaunchKernelGGL(dgt_prep, dim3((WB_U32 + 255) / 256), dim3(256),
                           0, stream, W_pred, Wb);
        hipLaunchKernelGGL(dgt_jump, dim3(BATCH / 32), dim3(256), 0, stream,
                           x, Wb, W_pred, b_pred, W_or, a_std, out);
    } else {
        hipLaunchKernelGGL(dgt_f32, dim3(BATCH / 32), dim3(256), 0, stream,
                           x, W_pred, b_pred, W_or, a_std, out);
    }
}